// Round 1
// baseline (186.055 us; speedup 1.0000x reference)
//
#include <hip/hip_runtime.h>
#include <hip/hip_bf16.h>

// RBF-KAN as one fused bf16 MFMA GEMM:
//   out[b,o] = sum_k A[b,k] * W[k,o] + bias[o]
//   k = ic*832 + slot*64 + ii, i = ic*64+ii
//   slot==0: A = x[b,i],            W = base_w[o,i]
//   slot>=1: A = basis(x[b,i],g),   W = coeff[i,o,g],  g = slot-1
// basis(x,g) = exp(-0.5*((x-c_g)/h)^2), c_g = -4 + g*h, h = 8/11
// With u = (x+4)/h = x*1.375 + 5.5:
//   basis_0 = exp(-u^2/2); basis_{g+1} = basis_g * f_g; f_0 = exp(u-0.5); f_{g+1} = f_g*e^-1

#define M_DIM 16384
#define N_DIM 512
#define I_DIM 512
#define KTOT  6656      // 8 chunks * 832
#define CHK   832       // 13 slots * 64

typedef short short8 __attribute__((ext_vector_type(8)));
typedef float f32x4 __attribute__((ext_vector_type(4)));

union S8u { short8 v; unsigned short u[8]; };

__device__ __forceinline__ unsigned short f2bf(float f) {
  union { float f; unsigned int u; } c; c.f = f;
  unsigned int r = (c.u + 0x7FFFu + ((c.u >> 16) & 1)) >> 16;  // RNE, finite inputs only
  return (unsigned short)r;
}

// ---------------- prep: repack coeff + base_w into bf16 W_ws[o][k] ----------------
__global__ __launch_bounds__(256) void prep_w(const float* __restrict__ coeff,
                                              const float* __restrict__ base_w,
                                              unsigned short* __restrict__ Wb) {
  int t = blockIdx.x * 256 + threadIdx.x;   // 512*6656/4 = 851968 threads
  int o = t / 1664;
  int k4 = (t - o * 1664) * 4;              // 4 consecutive k, never crosses a slot
  int ic = k4 / 832;
  int rem = k4 - ic * 832;
  int slot = rem >> 6;
  int ii = rem & 63;
  int i = ic * 64 + ii;
  float v0, v1, v2, v3;
  if (slot == 0) {
    const float4 bw = *(const float4*)(base_w + (size_t)o * I_DIM + i);
    v0 = bw.x; v1 = bw.y; v2 = bw.z; v3 = bw.w;
  } else {
    int g = slot - 1;
    const float* cp = coeff + (size_t)i * (N_DIM * 12) + o * 12 + g;
    v0 = cp[0]; v1 = cp[6144]; v2 = cp[2 * 6144]; v3 = cp[3 * 6144];
  }
  ushort4 s;
  s.x = f2bf(v0); s.y = f2bf(v1); s.z = f2bf(v2); s.w = f2bf(v3);
  *(ushort4*)(Wb + (size_t)o * KTOT + k4) = s;
}

// ---------------- MFMA phase: 16 ds_read_b128 + 32 mfma per K-step ----------------
__device__ __forceinline__ void mfma_step(const unsigned short* As,
                                          const unsigned short* Bs,
                                          f32x4 (&acc)[4][4],
                                          int rA, int cB, int kq, int swr) {
#pragma unroll
  for (int ks = 0; ks < 2; ++ks) {
    short8 af[4], bfv[4];
    const int kb = (ks * 64 + kq) ^ swr;    // byte offset of 16B k-subgroup, swizzled
#pragma unroll
    for (int m = 0; m < 4; ++m)
      af[m] = *(const short8*)((const char*)As + (rA + m * 16) * 128 + kb);
#pragma unroll
    for (int n = 0; n < 4; ++n)
      bfv[n] = *(const short8*)((const char*)Bs + (cB + n * 16) * 128 + kb);
#pragma unroll
    for (int m = 0; m < 4; ++m)
#pragma unroll
      for (int n = 0; n < 4; ++n)
        acc[m][n] = __builtin_amdgcn_mfma_f32_16x16x32_bf16(af[m], bfv[n], acc[m][n], 0, 0, 0);
  }
}

// ---------------- main fused GEMM ----------------
__global__ __launch_bounds__(256, 2) void kan_gemm(const float* __restrict__ x,
                                                   const unsigned short* __restrict__ Wb,
                                                   const float* __restrict__ bias,
                                                   float* __restrict__ out) {
  // [row][kk] bf16, row stride 128B, byte ^= (row&7)<<4 swizzle (T2)
  __shared__ unsigned short Asw[128 * 64];
  __shared__ unsigned short Bsw[128 * 64];

  const int tid  = threadIdx.x;
  const int lane = tid & 63;
  const int wid  = tid >> 6;
  const int wm   = wid >> 1, wn = wid & 1;

  const int rb = blockIdx.x >> 2;           // 128 row-blocks
  const int cb = blockIdx.x & 3;            // 4 col-blocks
  const int M0 = rb * 128;
  const int N0 = cb * 128;

  // staging map: thread -> (row r, half h), 32 k-elements each
  const int r = tid >> 1;
  const int h = tid & 1;
  const float* xg = x + (size_t)(M0 + r) * I_DIM + h * 32;

  // A-tile write pointers (constant across steps)
  char* aw[4];
#pragma unroll
  for (int q = 0; q < 4; ++q) {
    int kk0 = h * 32 + q * 8;
    aw[q] = (char*)Asw + r * 128 + ((kk0 * 2) ^ ((r & 7) << 4));
  }

  // B-tile global_load_lds: linear LDS dest + inverse-swizzled global source
  const int cg = lane >> 3;                 // 0..7 col within 8-col group
  const int uu = lane & 7;                  // 16B unit within 128B row
  const unsigned short* bsrc[4];
  unsigned short* bdst[4];
#pragma unroll
  for (int q = 0; q < 4; ++q) {
    int c0 = wid * 32 + q * 8;
    bsrc[q] = Wb + (size_t)(N0 + c0 + cg) * KTOT + ((uu ^ cg) << 3);
    bdst[q] = Bsw + c0 * 64;
  }

  f32x4 acc[4][4];
#pragma unroll
  for (int m = 0; m < 4; ++m)
#pragma unroll
    for (int n = 0; n < 4; ++n) acc[m][n] = (f32x4){0.f, 0.f, 0.f, 0.f};

  const int swr = (lane & 7) << 4;
  const int rA  = wm * 64 + (lane & 15);
  const int cB  = wn * 64 + (lane & 15);
  const int kq  = (lane >> 4) * 16;

  float4 xq[8];
#pragma unroll
  for (int q = 0; q < 8; ++q) xq[q] = *(const float4*)(xg + q * 4);   // chunk 0

  float bb[32], ff[32];

  for (int ic = 0; ic < 8; ++ic) {
    const int kbase = ic * CHK;

    // ---- slot 0: base (A = x), init basis recurrences ----
    {
      unsigned short a16[32];
      float xs[32];
#pragma unroll
      for (int q = 0; q < 8; ++q) {
        xs[q*4+0] = xq[q].x; xs[q*4+1] = xq[q].y; xs[q*4+2] = xq[q].z; xs[q*4+3] = xq[q].w;
      }
#pragma unroll
      for (int j = 0; j < 32; ++j) {
        float xv = xs[j];
        a16[j] = f2bf(xv);
        float u = fmaf(xv, 1.375f, 5.5f);                       // (x+4)/h exactly
        bb[j] = exp2f(-0.72134752044448170f * u * u);           // exp(-u^2/2)
        ff[j] = exp2f(fmaf(u, 1.44269504088896340f, -0.72134752044448170f)); // exp(u-1/2)
      }
      if (ic < 7) {                                             // xq dead: prefetch next chunk
        const float* xn = xg + (ic + 1) * 64;
#pragma unroll
        for (int q = 0; q < 8; ++q) xq[q] = *(const float4*)(xn + q * 4);
      }
#pragma unroll
      for (int q = 0; q < 4; ++q) {
        S8u s;
#pragma unroll
        for (int e = 0; e < 8; ++e) s.u[e] = a16[q * 8 + e];
        *(short8*)aw[q] = s.v;
      }
#pragma unroll
      for (int q = 0; q < 4; ++q)
        __builtin_amdgcn_global_load_lds(
            (const __attribute__((address_space(1))) void*)(bsrc[q] + kbase),
            (__attribute__((address_space(3))) void*)bdst[q], 16, 0, 0);
      __syncthreads();
      mfma_step(Asw, Bsw, acc, rA, cB, kq, swr);
      __syncthreads();
    }

    // ---- slots 1..12: basis for g = slot-1, 2 muls + cvt per element ----
#pragma unroll 2
    for (int slot = 1; slot < 13; ++slot) {
      unsigned short a16[32];
#pragma unroll
      for (int j = 0; j < 32; ++j) {
        a16[j] = f2bf(bb[j]);
        bb[j] *= ff[j];
        ff[j] *= 0.36787944117144233f;      // e^-1
      }
#pragma unroll
      for (int q = 0; q < 4; ++q) {
        S8u s;
#pragma unroll
        for (int e = 0; e < 8; ++e) s.u[e] = a16[q * 8 + e];
        *(short8*)aw[q] = s.v;
      }
      const int k0 = kbase + slot * 64;
#pragma unroll
      for (int q = 0; q < 4; ++q)
        __builtin_amdgcn_global_load_lds(
            (const __attribute__((address_space(1))) void*)(bsrc[q] + k0),
            (__attribute__((address_space(3))) void*)bdst[q], 16, 0, 0);
      __syncthreads();
      mfma_step(Asw, Bsw, acc, rA, cB, kq, swr);
      __syncthreads();
    }
  }

  // ---- epilogue: bias + store (C/D: col = lane&15, row = (lane>>4)*4 + reg) ----
  float bv[4];
#pragma unroll
  for (int n = 0; n < 4; ++n) bv[n] = bias[N0 + wn * 64 + n * 16 + (lane & 15)];
#pragma unroll
  for (int m = 0; m < 4; ++m) {
    int row0 = M0 + wm * 64 + m * 16 + (lane >> 4) * 4;
#pragma unroll
    for (int n = 0; n < 4; ++n) {
      int col = N0 + wn * 64 + n * 16 + (lane & 15);
      float* op = out + (size_t)row0 * N_DIM + col;
#pragma unroll
      for (int rg = 0; rg < 4; ++rg)
        op[(size_t)rg * N_DIM] = acc[m][n][rg] + bv[n];
    }
  }
}

extern "C" void kernel_launch(void* const* d_in, const int* in_sizes, int n_in,
                              void* d_out, int out_size, void* d_ws, size_t ws_size,
                              hipStream_t stream) {
  const float* x      = (const float*)d_in[0];
  const float* coeff  = (const float*)d_in[1];
  const float* base_w = (const float*)d_in[2];
  const float* base_b = (const float*)d_in[3];
  // d_in[4] (centers) is implied by u = x*1.375 + 5.5 (exact)
  unsigned short* Wb = (unsigned short*)d_ws;   // needs 6,815,744 B

  prep_w<<<3328, 256, 0, stream>>>(coeff, base_w, Wb);
  kan_gemm<<<512, 256, 0, stream>>>(x, Wb, base_b, (float*)d_out);
}

// Round 2
// 144.181 us; speedup vs baseline: 1.2904x; 1.2904x over previous
//
#include <hip/hip_runtime.h>
#include <hip/hip_bf16.h>

// RBF-KAN as one fused bf16 MFMA GEMM:
//   out[b,o] = sum_k A[b,k] * W[k,o] + bias[o]
//   k = ic*832 + slot*64 + ii, i = ic*64+ii
//   slot==0: A = x[b,i],            W = base_w[o,i]
//   slot>=1: A = basis(x[b,i],g),   W = coeff[i,o,g],  g = slot-1
// basis(x,g) = exp(-0.5*((x-c_g)/h)^2), c_g = -4 + g*h, h = 8/11
// u = (x+4)/h = x*1.375 + 5.5 (exact):
//   basis_0 = exp(-u^2/2); basis_{g+1} = basis_g * f_g; f_0 = exp(u-0.5); f_{g+1} = f_g*e^-1
//
// Round 2: BM=128 x BN=256 tile, 512 thr (8 waves 2x4), 32x32x16 MFMA,
// double-buffered LDS with single barrier/K-step, cvt_pk bf16 packing.

#define M_DIM 16384
#define N_DIM 512
#define I_DIM 512
#define KTOT  6656      // 104 K-steps of 64
#define NSTEP 104

typedef short short8 __attribute__((ext_vector_type(8)));
typedef float f32x16 __attribute__((ext_vector_type(16)));
typedef unsigned int u32x4 __attribute__((ext_vector_type(4)));

#define CVTPK(dst, lo, hi) \
  asm("v_cvt_pk_bf16_f32 %0, %1, %2" : "=v"(dst) : "v"(lo), "v"(hi))

__device__ __forceinline__ unsigned short f2bf(float f) {
  union { float f; unsigned int u; } c; c.f = f;
  unsigned int r = (c.u + 0x7FFFu + ((c.u >> 16) & 1)) >> 16;  // RNE, finite only
  return (unsigned short)r;
}

// ---------------- prep: repack coeff + base_w into bf16 W_ws[o][k] ----------------
__global__ __launch_bounds__(256) void prep_w(const float* __restrict__ coeff,
                                              const float* __restrict__ base_w,
                                              unsigned short* __restrict__ Wb) {
  int t = blockIdx.x * 256 + threadIdx.x;   // 512*6656/4 = 851968 threads
  int o = t / 1664;
  int k4 = (t - o * 1664) * 4;              // 4 consecutive k, never crosses a slot
  int ic = k4 / 832;
  int rem = k4 - ic * 832;
  int slot = rem >> 6;
  int ii = rem & 63;
  int i = ic * 64 + ii;
  float v0, v1, v2, v3;
  if (slot == 0) {
    const float4 bw = *(const float4*)(base_w + (size_t)o * I_DIM + i);
    v0 = bw.x; v1 = bw.y; v2 = bw.z; v3 = bw.w;
  } else {
    int g = slot - 1;
    const float* cp = coeff + (size_t)i * (N_DIM * 12) + o * 12 + g;
    v0 = cp[0]; v1 = cp[6144]; v2 = cp[2 * 6144]; v3 = cp[3 * 6144];
  }
  ushort4 s;
  s.x = f2bf(v0); s.y = f2bf(v1); s.z = f2bf(v2); s.w = f2bf(v3);
  *(ushort4*)(Wb + (size_t)o * KTOT + k4) = s;
}

// ---------------- main fused GEMM ----------------
__global__ __launch_bounds__(512, 2) void kan_gemm(const float* __restrict__ x,
                                                   const unsigned short* __restrict__ Wb,
                                                   const float* __restrict__ bias,
                                                   float* __restrict__ out) {
  // [row][kk] bf16, row stride 128B, byte ^= (row&7)<<4 swizzle (T2), double-buffered
  __shared__ unsigned short Asw[2][128 * 64];   // 2 x 16 KB
  __shared__ unsigned short Bsw[2][256 * 64];   // 2 x 32 KB

  const int tid  = threadIdx.x;
  const int lane = tid & 63;
  const int wid  = tid >> 6;
  const int wm   = wid >> 2, wn = wid & 3;      // 2 x 4 waves, 64x64 tiles

  const int rb = blockIdx.x >> 1;               // 128 row-blocks
  const int cb = blockIdx.x & 1;                // 2 col-blocks
  const int M0 = rb * 128;
  const int N0 = cb * 256;

  // ---- A staging map: thread -> (row sr, k-quarter skq), 16 elems each ----
  const int sr  = tid >> 2;                     // 0..127
  const int skq = tid & 3;                      // 16 k each
  const float* xg = x + (size_t)(M0 + sr) * I_DIM + skq * 16;
  const int aswz  = (sr & 7) << 4;
  const int aoff0 = sr * 128 + ((skq * 32) ^ aswz);
  const int aoff1 = sr * 128 + ((skq * 32 + 16) ^ aswz);

  // ---- B staging: global_load_lds, linear dest + inverse-swizzled source ----
  const int cg = lane >> 3;                     // col within 8-col group
  const int uu = lane & 7;                      // 16B unit within 128B row
  const unsigned short* bsrc[4];
  int bdstoff[4];
#pragma unroll
  for (int q = 0; q < 4; ++q) {
    int c0 = wid * 32 + q * 8;
    bsrc[q] = Wb + (size_t)(N0 + c0 + cg) * KTOT + ((uu ^ cg) << 3);
    bdstoff[q] = c0 * 64;
  }

  // ---- compute-side offsets (32x32x16: A row = lane&31, k = (lane>>5)*8+e) ----
  const int l31  = lane & 31;
  const int rswz = (lane & 7) << 4;
  const int kc   = (lane >> 5) * 16;            // byte offset of 8-elem k-group
  const int aro0 = (wm * 64 + l31) * 128;
  const int aro1 = aro0 + 32 * 128;
  const int bro0 = (wn * 64 + l31) * 128;
  const int bro1 = bro0 + 32 * 128;

  f32x16 acc[2][2];
#pragma unroll
  for (int i = 0; i < 2; ++i)
#pragma unroll
    for (int j = 0; j < 2; ++j)
#pragma unroll
      for (int r = 0; r < 16; ++r) acc[i][j][r] = 0.f;

  // ---- A-gen state ----
  float4 xq[4];
#pragma unroll
  for (int q = 0; q < 4; ++q) xq[q] = *(const float4*)(xg + q * 4);  // chunk 0
  float bb[16], ff[16];
  int gslot = 0, gic = 0;

  auto emitA = [&](char* pA) {
    unsigned int w[8];
    if (gslot == 0) {
      float f[16];
#pragma unroll
      for (int q = 0; q < 4; ++q) {
        f[q*4+0] = xq[q].x; f[q*4+1] = xq[q].y; f[q*4+2] = xq[q].z; f[q*4+3] = xq[q].w;
      }
#pragma unroll
      for (int j = 0; j < 8; ++j) CVTPK(w[j], f[2*j], f[2*j+1]);
      *(u32x4*)(pA + aoff0) = (u32x4){w[0], w[1], w[2], w[3]};
      *(u32x4*)(pA + aoff1) = (u32x4){w[4], w[5], w[6], w[7]};
#pragma unroll
      for (int j = 0; j < 16; ++j) {
        float u = fmaf(f[j], 1.375f, 5.5f);
        bb[j] = exp2f(-0.72134752044448170f * u * u);                         // exp(-u^2/2)
        ff[j] = exp2f(fmaf(u, 1.44269504088896340f, -0.72134752044448170f)); // exp(u-1/2)
      }
      if (gic < 7) {                            // xq consumed: prefetch next chunk
        const float* xn = xg + (gic + 1) * 64;
#pragma unroll
        for (int q = 0; q < 4; ++q) xq[q] = *(const float4*)(xn + q * 4);
        ++gic;
      }
    } else {
#pragma unroll
      for (int j = 0; j < 8; ++j) CVTPK(w[j], bb[2*j], bb[2*j+1]);
      *(u32x4*)(pA + aoff0) = (u32x4){w[0], w[1], w[2], w[3]};
      *(u32x4*)(pA + aoff1) = (u32x4){w[4], w[5], w[6], w[7]};
#pragma unroll
      for (int j = 0; j < 16; ++j) {
        bb[j] *= ff[j];
        ff[j] *= 0.36787944117144233f;          // e^-1
      }
    }
    gslot = (gslot == 12) ? 0 : gslot + 1;
  };

  // ---- prologue: fill buffer 0 with K-step 0 ----
  emitA((char*)&Asw[0][0]);
#pragma unroll
  for (int q = 0; q < 4; ++q)
    __builtin_amdgcn_global_load_lds(
        (const __attribute__((address_space(1))) void*)(bsrc[q]),
        (__attribute__((address_space(3))) void*)(&Bsw[0][bdstoff[q]]), 16, 0, 0);
  __syncthreads();

  // ---- main loop: stage t+1 into buf^1, compute t from buf, one barrier ----
  int buf = 0;
  for (int ks = 0; ks < NSTEP; ++ks) {
    const int nxt = buf ^ 1;
    if (ks < NSTEP - 1) {
      const size_t ko = (size_t)(ks + 1) * 64;
#pragma unroll
      for (int q = 0; q < 4; ++q)
        __builtin_amdgcn_global_load_lds(
            (const __attribute__((address_space(1))) void*)(bsrc[q] + ko),
            (__attribute__((address_space(3))) void*)(&Bsw[nxt][bdstoff[q]]), 16, 0, 0);
      emitA((char*)&Asw[nxt][0]);
    }
    const char* pA = (const char*)&Asw[buf][0];
    const char* pB = (const char*)&Bsw[buf][0];
#pragma unroll
    for (int s = 0; s < 4; ++s) {
      const int cbyte = (s * 32 + kc) ^ rswz;
      short8 a0 = *(const short8*)(pA + aro0 + cbyte);
      short8 a1 = *(const short8*)(pA + aro1 + cbyte);
      short8 b0 = *(const short8*)(pB + bro0 + cbyte);
      short8 b1 = *(const short8*)(pB + bro1 + cbyte);
      acc[0][0] = __builtin_amdgcn_mfma_f32_32x32x16_bf16(a0, b0, acc[0][0], 0, 0, 0);
      acc[0][1] = __builtin_amdgcn_mfma_f32_32x32x16_bf16(a0, b1, acc[0][1], 0, 0, 0);
      acc[1][0] = __builtin_amdgcn_mfma_f32_32x32x16_bf16(a1, b0, acc[1][0], 0, 0, 0);
      acc[1][1] = __builtin_amdgcn_mfma_f32_32x32x16_bf16(a1, b1, acc[1][1], 0, 0, 0);
    }
    __syncthreads();
    buf = nxt;
  }

  // ---- epilogue: C/D 32x32 layout: col=lane&31, row=(r&3)+8*(r>>2)+4*(lane>>5) ----
  float bv[2];
#pragma unroll
  for (int fn = 0; fn < 2; ++fn) bv[fn] = bias[N0 + wn * 64 + fn * 32 + l31];
  const int rbase = (lane >> 5) * 4;
#pragma unroll
  for (int fm = 0; fm < 2; ++fm) {
#pragma unroll
    for (int fn = 0; fn < 2; ++fn) {
      const size_t cix = (size_t)(N0 + wn * 64 + fn * 32 + l31);
#pragma unroll
      for (int r = 0; r < 16; ++r) {
        int row = M0 + wm * 64 + fm * 32 + (r & 3) + 8 * (r >> 2) + rbase;
        out[(size_t)row * N_DIM + cix] = acc[fm][fn][r] + bv[fn];
      }
    }
  }
}

extern "C" void kernel_launch(void* const* d_in, const int* in_sizes, int n_in,
                              void* d_out, int out_size, void* d_ws, size_t ws_size,
                              hipStream_t stream) {
  const float* x      = (const float*)d_in[0];
  const float* coeff  = (const float*)d_in[1];
  const float* base_w = (const float*)d_in[2];
  const float* base_b = (const float*)d_in[3];
  // d_in[4] (centers) is implied by u = x*1.375 + 5.5 (exact)
  unsigned short* Wb = (unsigned short*)d_ws;   // needs 6,815,744 B

  prep_w<<<3328, 256, 0, stream>>>(coeff, base_w, Wb);
  kan_gemm<<<256, 512, 0, stream>>>(x, Wb, base_b, (float*)d_out);
}

// Round 3
// 138.039 us; speedup vs baseline: 1.3478x; 1.0445x over previous
//
#include <hip/hip_runtime.h>
#include <hip/hip_bf16.h>

// RBF-KAN as one fused bf16 MFMA GEMM:
//   out[b,o] = sum_k A[b,k] * W[k,o] + bias[o]
//   k = ic*832 + slot*64 + ii, i = ic*64+ii
//   slot==0: A = x[b,i],            W = base_w[o,i]
//   slot>=1: A = basis(x[b,i],g),   W = coeff[i,o,g],  g = slot-1
// basis(x,g) = exp(-0.5*((x-c_g)/h)^2), c_g = -4 + g*h, h = 8/11
// u = (x+4)/h = x*1.375 + 5.5 (exact):
//   basis_0 = exp(-u^2/2); basis_{g+1} = basis_g * f_g; f_0 = exp(u-0.5); f_{g+1} = f_g*e^-1
//
// Round 3: k-granule-blocked LDS layout [kg][row][16B] -> every LDS access is
// base + lane*16 sequential (conflict-free by construction, no XOR swizzle).
// Wb repacked granule-major so global_load_lds sources stay contiguous.

#define M_DIM 16384
#define N_DIM 512
#define I_DIM 512
#define KTOT  6656      // 104 K-steps of 64
#define NSTEP 104

typedef short short8 __attribute__((ext_vector_type(8)));
typedef float f32x16 __attribute__((ext_vector_type(16)));
typedef unsigned int u32x4 __attribute__((ext_vector_type(4)));

#define CVTPK(dst, lo, hi) \
  asm("v_cvt_pk_bf16_f32 %0, %1, %2" : "=v"(dst) : "v"(lo), "v"(hi))

__device__ __forceinline__ unsigned short f2bf(float f) {
  union { float f; unsigned int u; } c; c.f = f;
  unsigned int r = (c.u + 0x7FFFu + ((c.u >> 16) & 1)) >> 16;  // RNE, finite only
  return (unsigned short)r;
}

// ---------------- prep: repack coeff + base_w into bf16 Wb2[g][o][e] ----------------
// g = k >> 3 (16B k-granule, 0..831), e = k & 7. Coalesced writes (consecutive
// threads -> consecutive 8B), reads as before.
__global__ __launch_bounds__(256) void prep_w(const float* __restrict__ coeff,
                                              const float* __restrict__ base_w,
                                              unsigned short* __restrict__ Wb2) {
  int t = blockIdx.x * 256 + threadIdx.x;   // 851968 threads, 4 shorts each
  int e0 = (t & 1) * 4;
  int go = t >> 1;                          // g*512 + o
  int o  = go & 511;
  int g  = go >> 9;
  int k4 = g * 8 + e0;                      // 4 consecutive k, same slot/granule
  int ic = k4 / 832;
  int rem = k4 - ic * 832;
  int slot = rem >> 6;
  int ii = rem & 63;
  int i = ic * 64 + ii;
  float v0, v1, v2, v3;
  if (slot == 0) {
    const float4 bw = *(const float4*)(base_w + (size_t)o * I_DIM + i);
    v0 = bw.x; v1 = bw.y; v2 = bw.z; v3 = bw.w;
  } else {
    int gg = slot - 1;
    const float* cp = coeff + (size_t)i * (N_DIM * 12) + o * 12 + gg;
    v0 = cp[0]; v1 = cp[6144]; v2 = cp[2 * 6144]; v3 = cp[3 * 6144];
  }
  ushort4 s;
  s.x = f2bf(v0); s.y = f2bf(v1); s.z = f2bf(v2); s.w = f2bf(v3);
  *(ushort4*)(Wb2 + (size_t)go * 8 + e0) = s;
}

// ---------------- main fused GEMM ----------------
__global__ __launch_bounds__(512, 2) void kan_gemm(const float* __restrict__ x,
                                                   const unsigned short* __restrict__ Wb2,
                                                   const float* __restrict__ bias,
                                                   float* __restrict__ out) {
  // k-granule-blocked: A [kg(8)][row(128)][8 bf16], B [kg(8)][col(256)][8 bf16]
  __shared__ unsigned short Asw[2][8 * 128 * 8];   // 2 x 16 KB
  __shared__ unsigned short Bsw[2][8 * 256 * 8];   // 2 x 32 KB

  const int tid  = threadIdx.x;
  const int lane = tid & 63;
  const int wid  = tid >> 6;
  const int wm   = wid >> 2, wn = wid & 3;      // 2 x 4 waves, 64x64 tiles

  const int rb = blockIdx.x >> 1;               // 128 row-blocks
  const int cb = blockIdx.x & 1;                // 2 col-blocks
  const int M0 = rb * 128;
  const int N0 = cb * 256;

  // ---- A staging map: thread -> (row, 16-i chunk kgp), 16 elems each ----
  const int arow = tid & 127;
  const int kgp  = tid >> 7;                    // 0..3 -> granules 2*kgp, 2*kgp+1
  const float* xg = x + (size_t)(M0 + arow) * I_DIM + kgp * 16;
  const int aoff0 = ((kgp * 2) * 128 + arow) * 16;      // byte offsets
  const int aoff1 = ((kgp * 2 + 1) * 128 + arow) * 16;

  // ---- B staging: wave w loads granule w, cols q*64..q*64+63 (contiguous 1KB) ----
  const unsigned short* bsrc[4];
  int bdst[4];
#pragma unroll
  for (int q = 0; q < 4; ++q) {
    bsrc[q] = Wb2 + ((size_t)wid * 512 + N0 + q * 64 + lane) * 8;  // + ks*32768
    bdst[q] = (wid * 256 + q * 64) * 16;                            // byte offset
  }

  // ---- compute-side byte offsets (32x32x16: row/col = lane&31, kg-half = lane>>5) ----
  const int l31 = lane & 31;
  const int aBase = ((lane >> 5) * 128 + wm * 64 + l31) * 16;
  const int bBase = ((lane >> 5) * 256 + wn * 64 + l31) * 16;

  f32x16 acc[2][2];
#pragma unroll
  for (int i = 0; i < 2; ++i)
#pragma unroll
    for (int j = 0; j < 2; ++j)
#pragma unroll
      for (int r = 0; r < 16; ++r) acc[i][j][r] = 0.f;

  // ---- A-gen state ----
  float4 xq[4];
#pragma unroll
  for (int q = 0; q < 4; ++q) xq[q] = *(const float4*)(xg + q * 4);  // chunk 0
  float bb[16], ff[16];
  int gslot = 0, gic = 0;

  auto emitA = [&](char* pA) {
    unsigned int w[8];
    if (gslot == 0) {
      float f[16];
#pragma unroll
      for (int q = 0; q < 4; ++q) {
        f[q*4+0] = xq[q].x; f[q*4+1] = xq[q].y; f[q*4+2] = xq[q].z; f[q*4+3] = xq[q].w;
      }
#pragma unroll
      for (int j = 0; j < 8; ++j) CVTPK(w[j], f[2*j], f[2*j+1]);
      *(u32x4*)(pA + aoff0) = (u32x4){w[0], w[1], w[2], w[3]};
      *(u32x4*)(pA + aoff1) = (u32x4){w[4], w[5], w[6], w[7]};
#pragma unroll
      for (int j = 0; j < 16; ++j) {
        float u = fmaf(f[j], 1.375f, 5.5f);
        bb[j] = exp2f(-0.72134752044448170f * u * u);                         // exp(-u^2/2)
        ff[j] = exp2f(fmaf(u, 1.44269504088896340f, -0.72134752044448170f)); // exp(u-1/2)
      }
      if (gic < 7) {                            // xq consumed: prefetch next chunk
        const float* xn = xg + (gic + 1) * 64;
#pragma unroll
        for (int q = 0; q < 4; ++q) xq[q] = *(const float4*)(xn + q * 4);
        ++gic;
      }
    } else {
#pragma unroll
      for (int j = 0; j < 8; ++j) CVTPK(w[j], bb[2*j], bb[2*j+1]);
      *(u32x4*)(pA + aoff0) = (u32x4){w[0], w[1], w[2], w[3]};
      *(u32x4*)(pA + aoff1) = (u32x4){w[4], w[5], w[6], w[7]};
#pragma unroll
      for (int j = 0; j < 16; ++j) {
        bb[j] *= ff[j];
        ff[j] *= 0.36787944117144233f;          // e^-1
      }
    }
    gslot = (gslot == 12) ? 0 : gslot + 1;
  };

  // ---- prologue: fill buffer 0 with K-step 0 ----
  emitA((char*)&Asw[0][0]);
#pragma unroll
  for (int q = 0; q < 4; ++q)
    __builtin_amdgcn_global_load_lds(
        (const __attribute__((address_space(1))) void*)(bsrc[q]),
        (__attribute__((address_space(3))) void*)((char*)&Bsw[0][0] + bdst[q]), 16, 0, 0);
  __syncthreads();

  // ---- main loop: stage t+1 into buf^1, compute t from buf, one barrier ----
  int buf = 0;
  for (int ks = 0; ks < NSTEP; ++ks) {
    const int nxt = buf ^ 1;
    if (ks < NSTEP - 1) {
      const size_t ko = (size_t)(ks + 1) * 32768;   // shorts per K-step of Wb2
#pragma unroll
      for (int q = 0; q < 4; ++q)
        __builtin_amdgcn_global_load_lds(
            (const __attribute__((address_space(1))) void*)(bsrc[q] + ko),
            (__attribute__((address_space(3))) void*)((char*)&Bsw[nxt][0] + bdst[q]), 16, 0, 0);
      emitA((char*)&Asw[nxt][0]);
    }
    const char* pA = (const char*)&Asw[buf][0];
    const char* pB = (const char*)&Bsw[buf][0];
#pragma unroll
    for (int s = 0; s < 4; ++s) {
      const char* a = pA + aBase + s * 4096;    // 2 granules * 128 rows * 16B
      const char* b = pB + bBase + s * 8192;    // 2 granules * 256 cols * 16B
      short8 a0 = *(const short8*)(a);
      short8 a1 = *(const short8*)(a + 512);    // +32 rows
      short8 b0 = *(const short8*)(b);
      short8 b1 = *(const short8*)(b + 512);    // +32 cols
      acc[0][0] = __builtin_amdgcn_mfma_f32_32x32x16_bf16(a0, b0, acc[0][0], 0, 0, 0);
      acc[0][1] = __builtin_amdgcn_mfma_f32_32x32x16_bf16(a0, b1, acc[0][1], 0, 0, 0);
      acc[1][0] = __builtin_amdgcn_mfma_f32_32x32x16_bf16(a1, b0, acc[1][0], 0, 0, 0);
      acc[1][1] = __builtin_amdgcn_mfma_f32_32x32x16_bf16(a1, b1, acc[1][1], 0, 0, 0);
    }
    __syncthreads();
    buf = nxt;
  }

  // ---- epilogue: C/D 32x32 layout: col=lane&31, row=(r&3)+8*(r>>2)+4*(lane>>5) ----
  float bv[2];
#pragma unroll
  for (int fn = 0; fn < 2; ++fn) bv[fn] = bias[N0 + wn * 64 + fn * 32 + l31];
  const int rbase = (lane >> 5) * 4;
#pragma unroll
  for (int fm = 0; fm < 2; ++fm) {
#pragma unroll
    for (int fn = 0; fn < 2; ++fn) {
      const size_t cix = (size_t)(N0 + wn * 64 + fn * 32 + l31);
#pragma unroll
      for (int r = 0; r < 16; ++r) {
        int row = M0 + wm * 64 + fm * 32 + (r & 3) + 8 * (r >> 2) + rbase;
        out[(size_t)row * N_DIM + cix] = acc[fm][fn][r] + bv[fn];
      }
    }
  }
}

extern "C" void kernel_launch(void* const* d_in, const int* in_sizes, int n_in,
                              void* d_out, int out_size, void* d_ws, size_t ws_size,
                              hipStream_t stream) {
  const float* x      = (const float*)d_in[0];
  const float* coeff  = (const float*)d_in[1];
  const float* base_w = (const float*)d_in[2];
  const float* base_b = (const float*)d_in[3];
  // d_in[4] (centers) is implied by u = x*1.375 + 5.5 (exact)
  unsigned short* Wb2 = (unsigned short*)d_ws;   // needs 6,815,744 B

  prep_w<<<3328, 256, 0, stream>>>(coeff, base_w, Wb2);
  kan_gemm<<<256, 512, 0, stream>>>(x, Wb2, base_b, (float*)d_out);
}